// Round 1
// baseline (1698.905 us; speedup 1.0000x reference)
//
#include <hip/hip_runtime.h>
#include <math.h>

#define BB 2
#define LL 144
#define DIN 1024
#define DT 150
#define NO 4

// ---------------------------------------------------------------------------
// K1: projections  sh/st/oh/ot[b,l,:] = x[b,l,:] @ W + bias
// grid 288 blocks (one per (b,l) row), 256 threads
// ---------------------------------------------------------------------------
__global__ __launch_bounds__(256) void proj_kernel(
    const float* __restrict__ x,
    const float* __restrict__ Wsh, const float* __restrict__ bsh,
    const float* __restrict__ Wst, const float* __restrict__ bst,
    const float* __restrict__ Woh, const float* __restrict__ boh,
    const float* __restrict__ Wot, const float* __restrict__ bot,
    float* __restrict__ sh, float* __restrict__ st,
    float* __restrict__ oh, float* __restrict__ ot) {
  __shared__ float xs[DIN];
  int m = blockIdx.x;  // b*144 + l
  const float* xrow = x + (size_t)m * DIN;
  for (int k = threadIdx.x; k < DIN; k += 256) xs[k] = xrow[k];
  __syncthreads();
  for (int n = threadIdx.x; n < 4 * DT; n += 256) {
    int p = n / DT, dt = n - p * DT;
    const float* W = (p == 0) ? Wsh : (p == 1) ? Wst : (p == 2) ? Woh : Wot;
    const float* bi = (p == 0) ? bsh : (p == 1) ? bst : (p == 2) ? boh : bot;
    float acc = bi[dt];
    for (int k = 0; k < DIN; ++k) acc += xs[k] * W[(size_t)k * DT + dt];
    float* out = (p == 0) ? sh : (p == 1) ? st : (p == 2) ? oh : ot;
    out[(size_t)m * DT + dt] = acc;
  }
}

// ---------------------------------------------------------------------------
// K2: stage1   w[zl,o,i,j] = sum_k sh[z0+zl,k] * W[o,i,k,j]
// grid (600 (o,i) pairs, ceil(Zcur/48)); block 256 = (16 tx=j, 16 ty=z)
// thread tile 3z x 10j
// ---------------------------------------------------------------------------
__global__ __launch_bounds__(256) void stage1_kernel(
    const float* __restrict__ shp,   // sh + (b*144+z0)*DT
    const float* __restrict__ Wt,    // W_tri (o,i,k,j)
    float* __restrict__ wbuf,        // [zl][o][i][j]
    int Zcur) {
  constexpr int KT = 30;
  __shared__ float a_lds[48 * KT];    // [zz][kk]
  __shared__ float b_lds[KT * 160];   // [kk][j] (padded to 160)
  int oi = blockIdx.x;                // o*150 + i
  int ztile = blockIdx.y * 48;
  const float* Wbase = Wt + (size_t)oi * (DT * DT);
  int tid = threadIdx.x;
  int tx = tid & 15, ty = tid >> 4;
  float acc[3][10];
#pragma unroll
  for (int a = 0; a < 3; ++a)
#pragma unroll
    for (int u = 0; u < 10; ++u) acc[a][u] = 0.f;

  for (int k0 = 0; k0 < DT; k0 += KT) {
    for (int e = tid; e < 48 * KT; e += 256) {
      int zz = e / KT, kk = e - zz * KT;
      int zl = ztile + zz;
      a_lds[e] = (zl < Zcur) ? shp[(size_t)zl * DT + k0 + kk] : 0.f;
    }
    for (int e = tid; e < KT * 160; e += 256) {
      int kk = e / 160, j = e - kk * 160;
      b_lds[e] = (j < DT) ? Wbase[(size_t)(k0 + kk) * DT + j] : 0.f;
    }
    __syncthreads();
    for (int kk = 0; kk < KT; ++kk) {
      float af[3], bf[10];
#pragma unroll
      for (int tm = 0; tm < 3; ++tm) af[tm] = a_lds[(ty + 16 * tm) * KT + kk];
#pragma unroll
      for (int u = 0; u < 10; ++u) bf[u] = b_lds[kk * 160 + tx + 16 * u];
#pragma unroll
      for (int tm = 0; tm < 3; ++tm)
#pragma unroll
        for (int u = 0; u < 10; ++u) acc[tm][u] += af[tm] * bf[u];
    }
    __syncthreads();
  }
  int o = oi / DT, i = oi - o * DT;
#pragma unroll
  for (int tm = 0; tm < 3; ++tm) {
    int zl = ztile + ty + 16 * tm;
    if (zl >= Zcur) continue;
    size_t base = ((size_t)(zl * NO + o) * DT + i) * DT;
#pragma unroll
    for (int u = 0; u < 10; ++u) {
      int j = tx + 16 * u;
      if (j < DT) wbuf[base + j] = acc[tm][u];
    }
  }
}

// ---------------------------------------------------------------------------
// K3: stage2   t[zo,i,y] = sum_j w[zo,i,j] * yproj[y,j]   (NT gemm)
// grid (2 i-tiles, Zcur*4); block 256 = (16 tx=y, 16 ty=i); thread tile 5i x 9y
// ---------------------------------------------------------------------------
__global__ __launch_bounds__(256) void stage2_kernel(
    const float* __restrict__ wbuf,
    const float* __restrict__ yproj,  // [y][j], 144x150
    float* __restrict__ tbuf) {       // [zo][i][y]
  constexpr int KT = 30;
  __shared__ float a_lds[80 * KT];    // [ii][jj]
  __shared__ float b_lds[144 * KT];   // [yy][jj]
  int i0 = blockIdx.x * 80;
  int zo = blockIdx.y;
  const float* A = wbuf + (size_t)zo * (DT * DT);
  int tid = threadIdx.x;
  int tx = tid & 15, ty = tid >> 4;
  float acc[5][9];
#pragma unroll
  for (int a = 0; a < 5; ++a)
#pragma unroll
    for (int u = 0; u < 9; ++u) acc[a][u] = 0.f;

  for (int j0 = 0; j0 < DT; j0 += KT) {
    for (int e = tid; e < 80 * KT; e += 256) {
      int ii = e / KT, jj = e - ii * KT;
      int i = i0 + ii;
      a_lds[e] = (i < DT) ? A[(size_t)i * DT + j0 + jj] : 0.f;
    }
    for (int e = tid; e < 144 * KT; e += 256) {
      int yy = e / KT, jj = e - yy * KT;
      b_lds[e] = yproj[(size_t)yy * DT + j0 + jj];
    }
    __syncthreads();
    for (int jj = 0; jj < KT; ++jj) {
      float af[5], bf[9];
#pragma unroll
      for (int tm = 0; tm < 5; ++tm) af[tm] = a_lds[(ty + 16 * tm) * KT + jj];
#pragma unroll
      for (int tn = 0; tn < 9; ++tn) bf[tn] = b_lds[(tx + 16 * tn) * KT + jj];
#pragma unroll
      for (int tm = 0; tm < 5; ++tm)
#pragma unroll
        for (int tn = 0; tn < 9; ++tn) acc[tm][tn] += af[tm] * bf[tn];
    }
    __syncthreads();
  }
#pragma unroll
  for (int tm = 0; tm < 5; ++tm) {
    int i = i0 + ty + 16 * tm;
    if (i >= DT) continue;
    size_t base = ((size_t)zo * DT + i) * LL;
#pragma unroll
    for (int tn = 0; tn < 9; ++tn) {
      int y = tx + 16 * tn;
      tbuf[base + y] = acc[tm][tn];
    }
  }
}

// ---------------------------------------------------------------------------
// K4: stage3 + mask + log_softmax, fused.
// VAR=0 (tri1): out[zl,x,y,o] = lsm_o( z<=x ? sum_i st[x,i]*t[zl,o,i,y] : 0 )
// VAR=1 (tri2): out[zl,x,y,o] = lsm_o( z<=x ? sum_i ot[y,i]*t[zl,o,i,x] : 0 )
// grid (3 x-tiles, 3 y-tiles, Zcur); block 256 = (16 tx=y, 16 ty=x)
// thread tile 4o x 3x x 3y; float4 stores
// ---------------------------------------------------------------------------
template <int VAR>
__global__ __launch_bounds__(256) void stage3_kernel(
    const float* __restrict__ tbuf,   // [zl][o][i][q]
    const float* __restrict__ projb,  // st_b (VAR0) / ot_b (VAR1): [p][i]
    float* __restrict__ outbase,      // out + tri_off + (b*144+z0)*144*144*4
    int z0) {
  constexpr int KT = 30;
  __shared__ float a_lds[48 * KT];        // [pp][ii]
  __shared__ float t_lds[NO * KT * 48];   // [o][ii][qq]
  int xt = blockIdx.x * 48;
  int yt = blockIdx.y * 48;
  int zl = blockIdx.z;
  int zg = z0 + zl;
  int tid = threadIdx.x;
  int tx = tid & 15, ty = tid >> 4;
  const float NLOG4 = -1.3862943611198906f;

  if (zg > xt + 47) {  // whole tile masked
    float4 v = make_float4(NLOG4, NLOG4, NLOG4, NLOG4);
#pragma unroll
    for (int tm = 0; tm < 3; ++tm) {
      int xg = xt + ty + 16 * tm;
#pragma unroll
      for (int tn = 0; tn < 3; ++tn) {
        int yg = yt + tx + 16 * tn;
        *(float4*)(outbase + (((size_t)zl * LL + xg) * LL + yg) * NO) = v;
      }
    }
    return;
  }

  float acc[NO][3][3];
#pragma unroll
  for (int o = 0; o < NO; ++o)
#pragma unroll
    for (int a = 0; a < 3; ++a)
#pragma unroll
      for (int c = 0; c < 3; ++c) acc[o][a][c] = 0.f;

  const float* tz = tbuf + (size_t)zl * NO * DT * LL;
  int pbase = (VAR == 0) ? xt : yt;
  int qbase = (VAR == 0) ? yt : xt;

  for (int i0 = 0; i0 < DT; i0 += KT) {
    for (int e = tid; e < 48 * KT; e += 256) {
      int pp = e / KT, ii = e - pp * KT;
      a_lds[e] = projb[(size_t)(pbase + pp) * DT + i0 + ii];
    }
    for (int e = tid; e < NO * KT * 48; e += 256) {
      int o = e / (KT * 48);
      int r = e - o * (KT * 48);
      int ii = r / 48, qq = r - ii * 48;
      t_lds[e] = tz[((size_t)o * DT + i0 + ii) * LL + qbase + qq];
    }
    __syncthreads();
    for (int ii = 0; ii < KT; ++ii) {
      if (VAR == 0) {
        float xf[3];
#pragma unroll
        for (int tm = 0; tm < 3; ++tm) xf[tm] = a_lds[(ty + 16 * tm) * KT + ii];
#pragma unroll
        for (int o = 0; o < NO; ++o)
#pragma unroll
          for (int tn = 0; tn < 3; ++tn) {
            float yv = t_lds[(o * KT + ii) * 48 + tx + 16 * tn];
#pragma unroll
            for (int tm = 0; tm < 3; ++tm) acc[o][tm][tn] += xf[tm] * yv;
          }
      } else {
        float yf[3];
#pragma unroll
        for (int tn = 0; tn < 3; ++tn) yf[tn] = a_lds[(tx + 16 * tn) * KT + ii];
#pragma unroll
        for (int o = 0; o < NO; ++o)
#pragma unroll
          for (int tm = 0; tm < 3; ++tm) {
            float xv = t_lds[(o * KT + ii) * 48 + ty + 16 * tm];
#pragma unroll
            for (int tn = 0; tn < 3; ++tn) acc[o][tm][tn] += xv * yf[tn];
          }
      }
    }
    __syncthreads();
  }

#pragma unroll
  for (int tm = 0; tm < 3; ++tm) {
    int xg = xt + ty + 16 * tm;
#pragma unroll
    for (int tn = 0; tn < 3; ++tn) {
      int yg = yt + tx + 16 * tn;
      float4 v;
      if (zg > xg) {
        v = make_float4(NLOG4, NLOG4, NLOG4, NLOG4);
      } else {
        float c0 = acc[0][tm][tn], c1 = acc[1][tm][tn];
        float c2 = acc[2][tm][tn], c3 = acc[3][tm][tn];
        float mx = fmaxf(fmaxf(c0, c1), fmaxf(c2, c3));
        float lse = mx + logf(expf(c0 - mx) + expf(c1 - mx) +
                              expf(c2 - mx) + expf(c3 - mx));
        v = make_float4(c0 - lse, c1 - lse, c2 - lse, c3 - lse);
      }
      *(float4*)(outbase + (((size_t)zl * LL + xg) * LL + yg) * NO) = v;
    }
  }
}

// ---------------------------------------------------------------------------
extern "C" void kernel_launch(void* const* d_in, const int* in_sizes, int n_in,
                              void* d_out, int out_size, void* d_ws,
                              size_t ws_size, hipStream_t stream) {
  const float* x = (const float*)d_in[0];
  const float* Wsh = (const float*)d_in[1];
  const float* bsh = (const float*)d_in[2];
  const float* Wst = (const float*)d_in[3];
  const float* bst = (const float*)d_in[4];
  const float* Woh = (const float*)d_in[5];
  const float* boh = (const float*)d_in[6];
  const float* Wot = (const float*)d_in[7];
  const float* bot = (const float*)d_in[8];
  const float* Wt1 = (const float*)d_in[9];
  const float* Wt2 = (const float*)d_in[10];

  float* ws = (float*)d_ws;
  float* sh = ws;
  float* st = ws + 43200;
  float* oh = ws + 86400;
  float* ot = ws + 129600;
  float* wbuf = ws + 172800;

  // per-z floats: w = 4*150*150 = 90000, t = 4*150*144 = 86400
  size_t avail = ws_size / sizeof(float);
  avail = (avail > 172800) ? (avail - 172800) : 0;
  int Zc = (int)(avail / 176400);
  if (Zc > LL) Zc = LL;
  if (Zc < 1) Zc = 1;
  float* tbuf = wbuf + (size_t)Zc * 90000;

  proj_kernel<<<288, 256, 0, stream>>>(x, Wsh, bsh, Wst, bst, Woh, boh, Wot,
                                       bot, sh, st, oh, ot);

  float* out0 = (float*)d_out;
  float* out1 = out0 + (size_t)BB * LL * LL * LL * NO;  // +23887872

  for (int b = 0; b < BB; ++b) {
    for (int z0 = 0; z0 < LL; z0 += Zc) {
      int Zcur = (Zc < LL - z0) ? Zc : (LL - z0);
      for (int tri = 0; tri < 2; ++tri) {
        const float* Wt = tri ? Wt2 : Wt1;
        const float* yp = (tri ? st : oh) + b * 21600;   // stage2 B operand
        const float* pp = (tri ? ot : st) + b * 21600;   // stage3 proj operand
        float* outX =
            (tri ? out1 : out0) + ((size_t)(b * LL + z0)) * LL * LL * NO;

        stage1_kernel<<<dim3(600, (Zcur + 47) / 48), 256, 0, stream>>>(
            sh + b * 21600 + z0 * DT, Wt, wbuf, Zcur);
        stage2_kernel<<<dim3(2, Zcur * NO), 256, 0, stream>>>(wbuf, yp, tbuf);
        if (tri == 0)
          stage3_kernel<0><<<dim3(3, 3, Zcur), 256, 0, stream>>>(tbuf, pp, outX,
                                                                 z0);
        else
          stage3_kernel<1><<<dim3(3, 3, Zcur), 256, 0, stream>>>(tbuf, pp, outX,
                                                                 z0);
      }
    }
  }
}

// Round 2
// 838.811 us; speedup vs baseline: 2.0254x; 2.0254x over previous
//
#include <hip/hip_runtime.h>
#include <hip/hip_bf16.h>
#include <math.h>

typedef unsigned short u16;
typedef __attribute__((ext_vector_type(8))) short bf16x8;
typedef __attribute__((ext_vector_type(4))) float f32x4;

static __device__ __forceinline__ u16 f2bf(float f) {
  __hip_bfloat16 h = __float2bfloat16(f);
  return *reinterpret_cast<u16*>(&h);
}

// ---------------------------------------------------------------------------
// proj: sh/st/oh/ot[b,l,:] = x[b,l,:] @ W + bias  -> bf16, K padded 150->160
// out layout: [4 proj][288 rows][160], pads ZERO (kills padded garbage later)
// ---------------------------------------------------------------------------
__global__ __launch_bounds__(256) void proj_kernel(
    const float* __restrict__ x,
    const float* __restrict__ W0, const float* __restrict__ b0,
    const float* __restrict__ W1, const float* __restrict__ b1,
    const float* __restrict__ W2, const float* __restrict__ b2,
    const float* __restrict__ W3, const float* __restrict__ b3,
    u16* __restrict__ out) {
  __shared__ float xs[1024];
  int m = blockIdx.x;
  const float* xr = x + (size_t)m * 1024;
  for (int k = threadIdx.x; k < 1024; k += 256) xs[k] = xr[k];
  __syncthreads();
  for (int n = threadIdx.x; n < 640; n += 256) {
    int p = n / 160, dt = n - p * 160;
    float acc = 0.f;
    if (dt < 150) {
      const float* W = (p == 0) ? W0 : (p == 1) ? W1 : (p == 2) ? W2 : W3;
      const float* bb = (p == 0) ? b0 : (p == 1) ? b1 : (p == 2) ? b2 : b3;
      acc = bb[dt];
      for (int k = 0; k < 1024; ++k) acc += xs[k] * W[k * 150 + dt];
    }
    out[((size_t)p * 288 + m) * 160 + dt] = f2bf(acc);
  }
}

// ---------------------------------------------------------------------------
// transpose W_tri [600 oi][150 k][150 j] fp32 -> WtT [600][160 j][160 k] bf16
// pads zeroed.
// ---------------------------------------------------------------------------
__global__ __launch_bounds__(256) void transw_kernel(
    const float* __restrict__ W, u16* __restrict__ WtT) {
  __shared__ float lds[150 * 151];
  int oi = blockIdx.x;
  const float* src = W + (size_t)oi * 22500;
  for (int t = threadIdx.x; t < 22500; t += 256) {
    int k = t / 150, j = t - k * 150;
    lds[k * 151 + j] = src[t];
  }
  __syncthreads();
  u16* dst = WtT + (size_t)oi * 25600;
  for (int t = threadIdx.x; t < 25600; t += 256) {
    int j = t / 160, k = t - j * 160;
    float v = (j < 150 && k < 150) ? lds[k * 151 + j] : 0.f;
    dst[t] = f2bf(v);
  }
}

// ---------------------------------------------------------------------------
// generic NT-GEMM, bf16 MFMA: C[m][n] = sum_k A[m][k]*B[n][k]
// M tile = 144, N tile = 160, K = 160. 6 waves (384thr): 3My x 2Nx,
// wave tile 48x80 = 3x5 frags of 16x16x32.
// STAGE 1: bi=oi (o*150+i), B=WtT+bi*25600, C=wbuf+(o*160+i)*160, cstride 102400
// STAGE 2: bi=zo,           B=wbuf+bi*25600, C=tbuf+bi*23040,     cstride 160
// ---------------------------------------------------------------------------
template <int STAGE>
__global__ __launch_bounds__(384) void gemm_nt(
    const u16* __restrict__ A, const u16* __restrict__ B,
    u16* __restrict__ C, int Mvalid) {
  __shared__ __align__(16) u16 lds_a[144 * 168];
  __shared__ __align__(16) u16 lds_b[160 * 168];
  int bi = blockIdx.x;
  size_t coff;
  int cstride;
  if (STAGE == 1) {
    int o = bi / 150, i = bi - o * 150;
    coff = ((size_t)o * 160 + i) * 160;
    cstride = 102400;
  } else {
    coff = (size_t)bi * 23040;
    cstride = 160;
  }
  u16* Cb = C + coff;
  const uint4* As = (const uint4*)A;
  const uint4* Bs = (const uint4*)(B + (size_t)bi * 25600);
  uint4* la4 = (uint4*)lds_a;
  uint4* lb4 = (uint4*)lds_b;
  int tid = threadIdx.x;
  for (int t = tid; t < 2880; t += 384) {  // A: 144 rows x 20 chunks
    int r = t / 20, cc = t - r * 20;
    uint4 v = {0u, 0u, 0u, 0u};
    if (r < Mvalid) v = As[t];
    la4[r * 21 + cc] = v;
  }
  for (int t = tid; t < 3200; t += 384) {  // B: 160 rows x 20 chunks
    int r = t / 20, cc = t - r * 20;
    lb4[r * 21 + cc] = Bs[t];
  }
  __syncthreads();
  int lane = tid & 63, wave = tid >> 6;
  int wy = wave >> 1, wx = wave & 1;
  int l16 = lane & 15, quad = lane >> 4;
  int abase = (wy * 48 + l16) * 168 + quad * 8;
  int bbase = (wx * 80 + l16) * 168 + quad * 8;
  f32x4 acc[3][5];
#pragma unroll
  for (int mi = 0; mi < 3; ++mi)
#pragma unroll
    for (int ni = 0; ni < 5; ++ni) acc[mi][ni] = (f32x4){0.f, 0.f, 0.f, 0.f};
#pragma unroll
  for (int k0 = 0; k0 < 160; k0 += 32) {
    bf16x8 af[3], bfr[5];
#pragma unroll
    for (int mi = 0; mi < 3; ++mi)
      af[mi] = *(const bf16x8*)&lds_a[abase + mi * 16 * 168 + k0];
#pragma unroll
    for (int ni = 0; ni < 5; ++ni)
      bfr[ni] = *(const bf16x8*)&lds_b[bbase + ni * 16 * 168 + k0];
#pragma unroll
    for (int mi = 0; mi < 3; ++mi)
#pragma unroll
      for (int ni = 0; ni < 5; ++ni)
        acc[mi][ni] = __builtin_amdgcn_mfma_f32_16x16x32_bf16(
            af[mi], bfr[ni], acc[mi][ni], 0, 0, 0);
  }
#pragma unroll
  for (int mi = 0; mi < 3; ++mi) {
    int row0 = wy * 48 + mi * 16 + quad * 4;
#pragma unroll
    for (int ni = 0; ni < 5; ++ni) {
      int col = wx * 80 + ni * 16 + l16;
#pragma unroll
      for (int r = 0; r < 4; ++r) {
        int row = row0 + r;
        if (row < Mvalid) Cb[(size_t)row * cstride + col] = f2bf(acc[mi][ni][r]);
      }
    }
  }
}

// ---------------------------------------------------------------------------
// stage3 + mask + log_softmax. Block 256 = 4 waves, wave = one o.
// C_o[x][y] = sum_i U_o[x][i] * V_o[y][i]
// VAR0: U=st (shared), V=t1[z,o][y][i].  VAR1: U=t2[z,o][x][i], V=ot (shared)
// ---------------------------------------------------------------------------
template <int VAR>
__global__ __launch_bounds__(256) void stage3_kernel(
    const u16* __restrict__ tb,  // [Zchunk][4][144][160]
    const u16* __restrict__ P,   // [144][160] proj (st for VAR0, ot for VAR1)
    float* __restrict__ out,     // + (b*144+z0)*144*144*4
    int z0) {
  __shared__ __align__(16) u16 lds[5 * 8064];  // [0]=P tile, [1+o]=t tiles
  int xt = blockIdx.x * 48, yt = blockIdx.y * 48, zl = blockIdx.z;
  int zg = z0 + zl;
  int tid = threadIdx.x;
  const float NL4 = -1.3862943611198906f;
  if (zg > xt + 47) {  // fully masked tile
    float4 v = make_float4(NL4, NL4, NL4, NL4);
    for (int p = tid; p < 2304; p += 256) {
      int xl = p / 48, yl = p - xl * 48;
      *(float4*)(out + (((size_t)zl * 144 + xt + xl) * 144 + yt + yl) * 4) = v;
    }
    return;
  }
  int pbase = (VAR == 0) ? xt : yt;
  int qbase = (VAR == 0) ? yt : xt;
  uint4* l4 = (uint4*)lds;
  const uint4* Ps = (const uint4*)(P + (size_t)pbase * 160);
  for (int t = tid; t < 960; t += 256) {  // P tile: 48 x 20 chunks
    int r = t / 20, cc = t - r * 20;
    l4[r * 21 + cc] = Ps[t];
  }
  for (int t = tid; t < 3840; t += 256) {  // 4 t-tiles
    int o = t / 960, rr = t - o * 960;
    int r = rr / 20, cc = rr - r * 20;
    const uint4* Ts =
        (const uint4*)(tb + ((size_t)(zl * 4 + o) * 144 + qbase) * 160);
    l4[(1 + o) * 1008 + r * 21 + cc] = Ts[r * 20 + cc];
  }
  __syncthreads();
  int lane = tid & 63, o = tid >> 6, l16 = lane & 15, quad = lane >> 4;
  const u16* la = (VAR == 0) ? lds : lds + (size_t)(1 + o) * 8064;
  const u16* lb = (VAR == 0) ? lds + (size_t)(1 + o) * 8064 : lds;
  f32x4 acc[3][3];
#pragma unroll
  for (int mi = 0; mi < 3; ++mi)
#pragma unroll
    for (int ni = 0; ni < 3; ++ni) acc[mi][ni] = (f32x4){0.f, 0.f, 0.f, 0.f};
#pragma unroll
  for (int k0 = 0; k0 < 160; k0 += 32) {
    bf16x8 af[3], bfr[3];
#pragma unroll
    for (int mi = 0; mi < 3; ++mi)
      af[mi] = *(const bf16x8*)&la[(mi * 16 + l16) * 168 + quad * 8 + k0];
#pragma unroll
    for (int ni = 0; ni < 3; ++ni)
      bfr[ni] = *(const bf16x8*)&lb[(ni * 16 + l16) * 168 + quad * 8 + k0];
#pragma unroll
    for (int mi = 0; mi < 3; ++mi)
#pragma unroll
      for (int ni = 0; ni < 3; ++ni)
        acc[mi][ni] = __builtin_amdgcn_mfma_f32_16x16x32_bf16(
            af[mi], bfr[ni], acc[mi][ni], 0, 0, 0);
  }
  __syncthreads();  // done reading operands; reuse LDS for o-exchange
  float* sf = (float*)lds;
#pragma unroll
  for (int mi = 0; mi < 3; ++mi)
#pragma unroll
    for (int ni = 0; ni < 3; ++ni)
#pragma unroll
      for (int r = 0; r < 4; ++r)
        sf[((mi * 16 + quad * 4 + r) * 48 + ni * 16 + l16) * 4 + o] =
            acc[mi][ni][r];
  __syncthreads();
  for (int p = tid; p < 2304; p += 256) {
    int xl = p / 48, yl = p - xl * 48;
    int xg = xt + xl;
    float4 v;
    if (zg > xg) {
      v = make_float4(NL4, NL4, NL4, NL4);
    } else {
      float c0 = sf[p * 4], c1 = sf[p * 4 + 1];
      float c2 = sf[p * 4 + 2], c3 = sf[p * 4 + 3];
      float mx = fmaxf(fmaxf(c0, c1), fmaxf(c2, c3));
      float l = mx + logf(expf(c0 - mx) + expf(c1 - mx) + expf(c2 - mx) +
                          expf(c3 - mx));
      v = make_float4(c0 - l, c1 - l, c2 - l, c3 - l);
    }
    *(float4*)(out + (((size_t)zl * 144 + xg) * 144 + yt + yl) * 4) = v;
  }
}

// ---------------------------------------------------------------------------
extern "C" void kernel_launch(void* const* d_in, const int* in_sizes, int n_in,
                              void* d_out, int out_size, void* d_ws,
                              size_t ws_size, hipStream_t stream) {
  const float* x = (const float*)d_in[0];
  const float* Wsh = (const float*)d_in[1];
  const float* bsh = (const float*)d_in[2];
  const float* Wst = (const float*)d_in[3];
  const float* bst = (const float*)d_in[4];
  const float* Woh = (const float*)d_in[5];
  const float* boh = (const float*)d_in[6];
  const float* Wot = (const float*)d_in[7];
  const float* bot = (const float*)d_in[8];
  const float* Wt1 = (const float*)d_in[9];
  const float* Wt2 = (const float*)d_in[10];

  u16* ws = (u16*)d_ws;
  u16* pAll = ws;                  // 4*288*160 = 184320 u16
  u16* WtT = ws + 184320;          // 600*160*160 = 15360000 u16
  u16* dyn = WtT + 15360000;
  size_t ws_u = ws_size / 2;
  size_t avail = (ws_u > 15544320) ? ws_u - 15544320 : 0;
  int Zc = (int)(avail / 194560);  // per-z: wbuf 102400 + tbuf 92160
  if (Zc > 144) Zc = 144;
  if (Zc < 1) Zc = 1;

  proj_kernel<<<288, 256, 0, stream>>>(x, Wsh, bsh, Wst, bst, Woh, boh, Wot,
                                       bot, pAll);

  float* out0 = (float*)d_out;
  float* out1 = out0 + (size_t)2 * 144 * 144 * 144 * 4;

  for (int tri = 0; tri < 2; ++tri) {
    transw_kernel<<<600, 256, 0, stream>>>(tri ? Wt2 : Wt1, WtT);
    for (int b = 0; b < 2; ++b) {
      const u16* pSh = pAll + (size_t)(0 * 288 + b * 144) * 160;
      const u16* pSt = pAll + (size_t)(1 * 288 + b * 144) * 160;
      const u16* pOh = pAll + (size_t)(2 * 288 + b * 144) * 160;
      const u16* pOt = pAll + (size_t)(3 * 288 + b * 144) * 160;
      const u16* pQ = tri ? pSt : pOh;  // stage2 A operand (q dim)
      const u16* pP = tri ? pOt : pSt;  // stage3 proj operand
      float* outX = (tri ? out1 : out0) + (size_t)b * 144 * 144 * 144 * 4;
      for (int z0 = 0; z0 < 144; z0 += Zc) {
        int Zcur = (Zc < 144 - z0) ? Zc : (144 - z0);
        u16* wbuf = dyn;
        u16* tbuf = dyn + (size_t)Zc * 102400;
        gemm_nt<1><<<600, 384, 0, stream>>>(pSh + (size_t)z0 * 160, WtT, wbuf,
                                            Zcur);
        gemm_nt<2><<<Zcur * 4, 384, 0, stream>>>(pQ, wbuf, tbuf, 144);
        dim3 g3(3, 3, Zcur);
        float* oz = outX + (size_t)z0 * 144 * 144 * 4;
        if (tri == 0)
          stage3_kernel<0><<<g3, 256, 0, stream>>>(tbuf, pP, oz, z0);
        else
          stage3_kernel<1><<<g3, 256, 0, stream>>>(tbuf, pP, oz, z0);
      }
    }
  }
}

// Round 3
// 713.866 us; speedup vs baseline: 2.3799x; 1.1750x over previous
//
#include <hip/hip_runtime.h>
#include <hip/hip_bf16.h>
#include <math.h>

typedef unsigned short u16;
typedef __attribute__((ext_vector_type(8))) short bf16x8;
typedef __attribute__((ext_vector_type(4))) float f32x4;

static __device__ __forceinline__ u16 f2bf(float f) {
  __hip_bfloat16 h = __float2bfloat16(f);
  return *reinterpret_cast<u16*>(&h);
}

// ---------------------------------------------------------------------------
// K0: x fp32 -> bf16 (288x1024)
// ---------------------------------------------------------------------------
__global__ __launch_bounds__(256) void conv_x(const float* __restrict__ x,
                                              u16* __restrict__ xb) {
  int idx = (blockIdx.x * 256 + threadIdx.x) * 4;
  float4 v = *(const float4*)(x + idx);
  ushort4 o;
  o.x = f2bf(v.x); o.y = f2bf(v.y); o.z = f2bf(v.z); o.w = f2bf(v.w);
  *(ushort4*)(xb + idx) = o;
}

// ---------------------------------------------------------------------------
// K0b: W_proj [1024][150] fp32 -> WT4 [p][160][1024] bf16, pads (j>=150) zero
// grid (16 ktiles of 64, 4 p)
// ---------------------------------------------------------------------------
__global__ __launch_bounds__(256) void trans_wp(
    const float* __restrict__ W0, const float* __restrict__ W1,
    const float* __restrict__ W2, const float* __restrict__ W3,
    u16* __restrict__ WT4) {
  __shared__ float lds[64 * 151];
  int kt = blockIdx.x, p = blockIdx.y;
  const float* W = (p == 0) ? W0 : (p == 1) ? W1 : (p == 2) ? W2 : W3;
  for (int t = threadIdx.x; t < 64 * 150; t += 256) {
    int k = t / 150, j = t - k * 150;
    lds[k * 151 + j] = W[(size_t)(kt * 64 + k) * 150 + j];
  }
  __syncthreads();
  u16* dst = WT4 + (size_t)p * 160 * 1024 + kt * 64;
  for (int t = threadIdx.x; t < 160 * 64; t += 256) {
    int j = t >> 6, kk = t & 63;
    float v = (j < 150) ? lds[kk * 151 + j] : 0.f;
    dst[(size_t)j * 1024 + kk] = f2bf(v);
  }
}

// ---------------------------------------------------------------------------
// transpose W_tri [600 oi][150 k][150 j] fp32 -> WtT [600][160 j][160 k] bf16
// ---------------------------------------------------------------------------
__global__ __launch_bounds__(256) void transw_kernel(
    const float* __restrict__ W, u16* __restrict__ WtT) {
  __shared__ float lds[150 * 151];
  int oi = blockIdx.x;
  const float* src = W + (size_t)oi * 22500;
  for (int t = threadIdx.x; t < 22500; t += 256) {
    int k = t / 150, j = t - k * 150;
    lds[k * 151 + j] = src[t];
  }
  __syncthreads();
  u16* dst = WtT + (size_t)oi * 25600;
  for (int t = threadIdx.x; t < 25600; t += 256) {
    int j = t / 160, k = t - j * 160;
    float v = (j < 150 && k < 150) ? lds[k * 151 + j] : 0.f;
    dst[t] = f2bf(v);
  }
}

// ---------------------------------------------------------------------------
// Unified NT-GEMM, bf16 MFMA. Block tile M144 x N80, 3 waves (192 thr),
// wave tile 48x80 (3x5 frags). LDS (144+80) rows, stride BK+8 (2-way = free).
// STAGE 0 (proj): K=1024 (BK=128, 8 iters). grid (8 ntile over 640, 2 mtile).
//   A=xb, B=WT4, C=pAll [p][288][160] + bias, pads j>=150 -> 0.
// STAGE 1: K=160 one-shot. grid (2 b, 2 ntile, 600 oi).
//   A=sh(z0)+b*23040, B=WtT[oi]+nt*80 rows, C=wbuf[b][z][o][i][j].
// STAGE 2: K=160 one-shot. grid (2 ntile, Zcur*4 f2=zl*4+o, 2 b).
//   A=pQ+b*23040, B=wbuf[b][f2], C=tbuf[b][f2][q][i].
// ---------------------------------------------------------------------------
template <int STAGE>
__global__ __launch_bounds__(192) void gemm_nt(
    const u16* __restrict__ A, const u16* __restrict__ B, u16* __restrict__ C,
    int Mvalid, int ZcapW, int ZcapT, const float* __restrict__ bias0,
    const float* __restrict__ bias1, const float* __restrict__ bias2,
    const float* __restrict__ bias3) {
  constexpr int BK = (STAGE == 0) ? 128 : 160;
  constexpr int NK = (STAGE == 0) ? 8 : 1;
  constexpr int ST = BK + 8;
  constexpr int C8 = BK / 8;
  constexpr int Astride = (STAGE == 0) ? 1024 : 160;
  constexpr int Bstride = (STAGE == 0) ? 1024 : 160;
  __shared__ __align__(16) u16 lds[224 * ST];
  const u16 *Ab, *Bb;
  u16* Cb = nullptr;
  int cstride = 0;
  if (STAGE == 0) {
    Ab = A + (size_t)blockIdx.y * 144 * 1024;
    Bb = B + (size_t)blockIdx.x * 80 * 1024;
  } else if (STAGE == 1) {
    int b = blockIdx.x, ntile = blockIdx.y, oi = blockIdx.z;
    int o = oi / 150, i = oi - o * 150;
    Ab = A + (size_t)b * 23040;
    Bb = B + (size_t)oi * 25600 + ntile * 12800;
    Cb = C + (size_t)b * ZcapW + ((size_t)o * 160 + i) * 160 + ntile * 80;
    cstride = 102400;
  } else {
    int ntile = blockIdx.x, f2 = blockIdx.y, b = blockIdx.z;
    Ab = A + (size_t)b * 23040;
    Bb = B + (size_t)b * ZcapW + (size_t)f2 * 25600 + ntile * 12800;
    Cb = C + (size_t)b * ZcapT + (size_t)f2 * 23040 + ntile * 80;
    cstride = 160;
  }
  int tid = threadIdx.x;
  int lane = tid & 63, wave = tid >> 6;
  int l16 = lane & 15, quad = lane >> 4;
  f32x4 acc[3][5];
#pragma unroll
  for (int mi = 0; mi < 3; ++mi)
#pragma unroll
    for (int ni = 0; ni < 5; ++ni) acc[mi][ni] = (f32x4){0.f, 0.f, 0.f, 0.f};

  for (int k0 = 0; k0 < NK; ++k0) {
    for (int t = tid; t < 144 * C8; t += 192) {
      int r = t / C8, c = t - r * C8;
      uint4 v = {0u, 0u, 0u, 0u};
      if (r < Mvalid)
        v = *(const uint4*)(Ab + (size_t)r * Astride + k0 * BK + c * 8);
      *(uint4*)&lds[r * ST + c * 8] = v;
    }
    for (int t = tid; t < 80 * C8; t += 192) {
      int r = t / C8, c = t - r * C8;
      uint4 v = *(const uint4*)(Bb + (size_t)r * Bstride + k0 * BK + c * 8);
      *(uint4*)&lds[(144 + r) * ST + c * 8] = v;
    }
    __syncthreads();
    const u16* la = lds + (wave * 48 + l16) * ST + quad * 8;
    const u16* lb = lds + (144 + l16) * ST + quad * 8;
#pragma unroll
    for (int ks = 0; ks < BK / 32; ++ks) {
      bf16x8 af[3], bfr[5];
#pragma unroll
      for (int mi = 0; mi < 3; ++mi)
        af[mi] = *(const bf16x8*)(la + mi * 16 * ST + ks * 32);
#pragma unroll
      for (int ni = 0; ni < 5; ++ni)
        bfr[ni] = *(const bf16x8*)(lb + ni * 16 * ST + ks * 32);
#pragma unroll
      for (int mi = 0; mi < 3; ++mi)
#pragma unroll
        for (int ni = 0; ni < 5; ++ni)
          acc[mi][ni] = __builtin_amdgcn_mfma_f32_16x16x32_bf16(
              af[mi], bfr[ni], acc[mi][ni], 0, 0, 0);
    }
    __syncthreads();
  }

  if (STAGE == 0) {
    int nbase = blockIdx.x * 80;
#pragma unroll
    for (int ni = 0; ni < 5; ++ni) {
      int n = nbase + ni * 16 + l16;
      int p = n / 160, j = n - p * 160;
      const float* bp =
          (p == 0) ? bias0 : (p == 1) ? bias1 : (p == 2) ? bias2 : bias3;
      bool live = (j < 150);
      float bv = live ? bp[j] : 0.f;
#pragma unroll
      for (int mi = 0; mi < 3; ++mi) {
        int row = blockIdx.y * 144 + wave * 48 + mi * 16 + quad * 4;
#pragma unroll
        for (int r = 0; r < 4; ++r) {
          float v = live ? acc[mi][ni][r] + bv : 0.f;
          C[((size_t)p * 288 + row + r) * 160 + j] = f2bf(v);
        }
      }
    }
  } else {
#pragma unroll
    for (int mi = 0; mi < 3; ++mi) {
      int grow0 = wave * 48 + mi * 16 + quad * 4;
#pragma unroll
      for (int ni = 0; ni < 5; ++ni)
#pragma unroll
        for (int r = 0; r < 4; ++r) {
          int grow = grow0 + r;
          if (grow < Mvalid)
            Cb[(size_t)grow * cstride + ni * 16 + l16] = f2bf(acc[mi][ni][r]);
        }
    }
  }
}

// ---------------------------------------------------------------------------
// stage3 + mask + log_softmax. Block 256 = 4 waves (wave = o).
// grid (6 = xtile*2+b, 3 ytile, Zcur). K=160 split 96+64 -> 49.9 KB LDS.
// VAR0: C[x][y] = sum_i st[x,i] * t1[z,o][y][i]
// VAR1: C[x][y] = sum_i t2[z,o][x][i] * ot[y,i]
// ---------------------------------------------------------------------------
template <int VAR>
__global__ __launch_bounds__(256) void stage3_kernel(
    const u16* __restrict__ tb, const u16* __restrict__ P,
    float* __restrict__ out, int z0, int ZcapT) {
  constexpr int ST = 104;
  __shared__ __align__(16) u16 lds[5 * 48 * ST];
  int bx = blockIdx.x;
  int b = bx & 1, xt = (bx >> 1) * 48;
  int yt = blockIdx.y * 48;
  int zl = blockIdx.z;
  int zg = z0 + zl;
  int tid = threadIdx.x;
  const float NL4 = -1.3862943611198906f;
  size_t obase = ((size_t)(b * 144 + zg)) * 82944;
  if (zg > xt + 47) {  // fully masked tile
    float4 v = make_float4(NL4, NL4, NL4, NL4);
    for (int p = tid; p < 2304; p += 256) {
      int xl = p / 48, yl = p - xl * 48;
      *(float4*)(out + obase + ((size_t)(xt + xl) * 144 + yt + yl) * 4) = v;
    }
    return;
  }
  int pbase = (VAR == 0) ? xt : yt;
  int qbase = (VAR == 0) ? yt : xt;
  const u16* Pb = P + (size_t)b * 23040 + (size_t)pbase * 160;
  const u16* Tz = tb + (size_t)b * ZcapT + (size_t)zl * 92160;
  int lane = tid & 63, o = tid >> 6, l16 = lane & 15, quad = lane >> 4;
  f32x4 acc[3][3];
#pragma unroll
  for (int mi = 0; mi < 3; ++mi)
#pragma unroll
    for (int ni = 0; ni < 3; ++ni) acc[mi][ni] = (f32x4){0.f, 0.f, 0.f, 0.f};

#pragma unroll
  for (int kb = 0; kb < 2; ++kb) {
    const int kbase = kb * 96;
    const int C8 = kb ? 8 : 12;
    for (int t = tid; t < 240 * C8; t += 256) {
      int tile = t / (48 * C8);
      int rr = t - tile * 48 * C8;
      int r = rr / C8, c = rr - r * C8;
      const u16* src =
          (tile == 0)
              ? (Pb + (size_t)r * 160 + kbase + c * 8)
              : (Tz + ((size_t)(tile - 1) * 144 + qbase + r) * 160 + kbase +
                 c * 8);
      *(uint4*)&lds[(tile * 48 + r) * ST + c * 8] = *(const uint4*)src;
    }
    __syncthreads();
    const u16* la;
    const u16* lb;
    if (VAR == 0) {
      la = lds;
      lb = lds + (1 + o) * 48 * ST;
    } else {
      la = lds + (1 + o) * 48 * ST;
      lb = lds;
    }
    const int NKS = kb ? 2 : 3;
#pragma unroll
    for (int ks = 0; ks < 3; ++ks) {
      if (ks >= NKS) break;
      bf16x8 af[3], bfr[3];
#pragma unroll
      for (int mi = 0; mi < 3; ++mi)
        af[mi] = *(const bf16x8*)&la[(mi * 16 + l16) * ST + ks * 32 + quad * 8];
#pragma unroll
      for (int ni = 0; ni < 3; ++ni)
        bfr[ni] =
            *(const bf16x8*)&lb[(ni * 16 + l16) * ST + ks * 32 + quad * 8];
#pragma unroll
      for (int mi = 0; mi < 3; ++mi)
#pragma unroll
        for (int ni = 0; ni < 3; ++ni)
          acc[mi][ni] = __builtin_amdgcn_mfma_f32_16x16x32_bf16(
              af[mi], bfr[ni], acc[mi][ni], 0, 0, 0);
    }
    __syncthreads();
  }

  float* sf = (float*)lds;
#pragma unroll
  for (int mi = 0; mi < 3; ++mi)
#pragma unroll
    for (int ni = 0; ni < 3; ++ni)
#pragma unroll
      for (int r = 0; r < 4; ++r)
        sf[((mi * 16 + quad * 4 + r) * 48 + ni * 16 + l16) * 4 + o] =
            acc[mi][ni][r];
  __syncthreads();
  for (int p = tid; p < 2304; p += 256) {
    int xl = p / 48, yl = p - xl * 48;
    int xg = xt + xl;
    float4 v;
    if (zg > xg) {
      v = make_float4(NL4, NL4, NL4, NL4);
    } else {
      float c0 = sf[p * 4], c1 = sf[p * 4 + 1];
      float c2 = sf[p * 4 + 2], c3 = sf[p * 4 + 3];
      float mx = fmaxf(fmaxf(c0, c1), fmaxf(c2, c3));
      float l = mx + logf(expf(c0 - mx) + expf(c1 - mx) + expf(c2 - mx) +
                          expf(c3 - mx));
      v = make_float4(c0 - l, c1 - l, c2 - l, c3 - l);
    }
    *(float4*)(out + obase + ((size_t)xg * 144 + yt + yl) * 4) = v;
  }
}

// ---------------------------------------------------------------------------
extern "C" void kernel_launch(void* const* d_in, const int* in_sizes, int n_in,
                              void* d_out, int out_size, void* d_ws,
                              size_t ws_size, hipStream_t stream) {
  const float* x = (const float*)d_in[0];
  const float* Wsh = (const float*)d_in[1];
  const float* bsh = (const float*)d_in[2];
  const float* Wst = (const float*)d_in[3];
  const float* bst = (const float*)d_in[4];
  const float* Woh = (const float*)d_in[5];
  const float* boh = (const float*)d_in[6];
  const float* Wot = (const float*)d_in[7];
  const float* bot = (const float*)d_in[8];
  const float* Wt1 = (const float*)d_in[9];
  const float* Wt2 = (const float*)d_in[10];

  u16* ws = (u16*)d_ws;
  u16* xb = ws;                   // 294912
  u16* WT4 = ws + 294912;         // 655360
  u16* pAll = ws + 950272;        // 184320 : [p][288][160]
  u16* WtT = ws + 1134592;        // 15360000
  u16* dyn = ws + 16494592;
  size_t ws_u = ws_size / 2;
  long long avail = (long long)ws_u - 16494592LL;
  int Zc = (avail > 0) ? (int)(avail / 389120) : 1;
  if (Zc > 144) Zc = 144;
  if (Zc < 1) Zc = 1;
  int ZcapW = Zc * 102400, ZcapT = Zc * 92160;
  u16* wbuf = dyn;
  u16* tbuf = dyn + (size_t)2 * ZcapW;

  conv_x<<<288, 256, 0, stream>>>(x, xb);
  trans_wp<<<dim3(16, 4), 256, 0, stream>>>(Wsh, Wst, Woh, Wot, WT4);
  gemm_nt<0><<<dim3(8, 2), 192, 0, stream>>>(xb, WT4, pAll, 144, 0, 0, bsh,
                                             bst, boh, bot);

  float* out0 = (float*)d_out;
  float* out1 = out0 + 23887872;  // 2*144^3*4

  for (int tri = 0; tri < 2; ++tri) {
    transw_kernel<<<600, 256, 0, stream>>>(tri ? Wt2 : Wt1, WtT);
    const u16* shsec = pAll;                                    // p0 = sh
    const u16* pQ = pAll + (size_t)(tri ? 1 : 2) * 46080;       // st : oh
    const u16* pP = pAll + (size_t)(tri ? 3 : 1) * 46080;       // ot : st
    float* outT = tri ? out1 : out0;
    for (int z0 = 0; z0 < 144; z0 += Zc) {
      int Zcur = (Zc < 144 - z0) ? Zc : (144 - z0);
      gemm_nt<1><<<dim3(2, 2, 600), 192, 0, stream>>>(
          shsec + (size_t)z0 * 160, WtT, wbuf, Zcur, ZcapW, 0, nullptr,
          nullptr, nullptr, nullptr);
      gemm_nt<2><<<dim3(2, Zcur * 4, 2), 192, 0, stream>>>(
          pQ, wbuf, tbuf, 144, ZcapW, ZcapT, nullptr, nullptr, nullptr,
          nullptr);
      dim3 g3(6, 3, Zcur);
      if (tri == 0)
        stage3_kernel<0><<<g3, 256, 0, stream>>>(tbuf, pP, outT, z0, ZcapT);
      else
        stage3_kernel<1><<<g3, 256, 0, stream>>>(tbuf, pP, outT, z0, ZcapT);
    }
  }
}